// Round 5
// baseline (540.789 us; speedup 1.0000x reference)
//
#include <hip/hip_runtime.h>
#include <hip/hip_bf16.h>

// CellSmooth R8:
//  - gemm8_kernel: back to R6 geometry (256x256xBK32, 512 thr, 8 waves 2x4,
//    register-pipelined frags, ring-3 A-LDS) but B (ET) is read DIRECTLY
//    from global into registers -- no B staging, no B ds_read.  R4-R7
//    showed MfmaUtil pinned at 50-57%: per K-tile per CU, LDS traffic
//    (64KB A-read x4 amp + 32KB B-read x2 amp + 32KB write ~ 1500 cyc)
//    exceeds the 1050-cyc MFMA cost, so the kernel was LDS-BW-bound and
//    no schedule could pass ~57%.  B-direct removes 48KB/K-tile of LDS
//    traffic (-> ~880 cyc < MFMA) and the wave's B-frag global read is 16
//    fully-used 64B segments (L2-clean, ET panel L2/L3-resident).
//    Occupancy note: acc(128 AGPR)+128 VGPR = 256 unified regs/wave ->
//    hard 2 waves/SIMD; keep __launch_bounds__(512,2) so allocator stays
//    at <=128 arch VGPRs.
//    vmcnt queue per thread: [Astage(u+2)x2] at top; body issues B(u+1)x4
//    then Astage(u+3)x2; tail wait vmcnt(2) leaves only Astage(u+3).
//    Same bf16 values and MFMA order as R6 -> bitwise-identical output.
//  - pk/prep/etrans/inv unchanged.  Legacy gemm_kernel retained as fallback.

typedef __attribute__((ext_vector_type(8))) short bf16x8;
typedef __attribute__((ext_vector_type(4))) float f32x4;
typedef __attribute__((ext_vector_type(16))) float f32x16;

constexpr int N_ = 8192;
constexpr int G_ = 2048;
constexpr int D_ = 64;

__device__ __forceinline__ unsigned short f32_to_bf16(float f) {
  unsigned u = __builtin_bit_cast(unsigned, f);
  u = (u + 0x7FFFu + ((u >> 16) & 1u)) >> 16;  // RTNE
  return (unsigned short)u;
}
__device__ __forceinline__ float bf16_to_f32(unsigned short h) {
  unsigned u = ((unsigned)h) << 16;
  return __builtin_bit_cast(float, u);
}

typedef __attribute__((address_space(1))) const unsigned int glob_u32;
typedef __attribute__((address_space(3))) unsigned int lds_u32;
__device__ __forceinline__ void gload_lds16(const void* g, void* l) {
  __builtin_amdgcn_global_load_lds((glob_u32*)g, (lds_u32*)l, 16, 0, 0);
}

// --- prep: row norms + packed (norm, quality) + enc -> bf16 ---
__global__ void prep_kernel(const float* __restrict__ enc,
                            const float* __restrict__ quality,
                            float* __restrict__ norms,
                            float2* __restrict__ nq,
                            unsigned short* __restrict__ encb) {
  int row = blockIdx.x * blockDim.x + threadIdx.x;
  if (row >= N_) return;
  const float* r = enc + (size_t)row * D_;
  float n = 0.f;
#pragma unroll
  for (int k = 0; k < D_; k += 4) {
    float4 v = *(const float4*)(r + k);
    n += v.x * v.x + v.y * v.y + v.z * v.z + v.w * v.w;
    ushort4 h;
    h.x = f32_to_bf16(v.x); h.y = f32_to_bf16(v.y);
    h.z = f32_to_bf16(v.z); h.w = f32_to_bf16(v.w);
    *(ushort4*)(encb + (size_t)row * D_ + k) = h;
  }
  norms[row] = n;
  nq[row] = make_float2(n, quality[row]);
}

// --- expression [N][G] f32 -> ET [G][N] bf16 (transpose+convert) ---
__global__ void etrans_kernel(const float* __restrict__ E,
                              unsigned short* __restrict__ ET) {
  __shared__ __align__(16) unsigned short t[64 * 72];
  int j0 = blockIdx.x * 64;
  int g0 = blockIdx.y * 64;
  int tid = threadIdx.x;
#pragma unroll
  for (int it = 0; it < 4; ++it) {
    int r = it * 16 + (tid >> 4);
    int c4 = tid & 15;
    float4 v = *(const float4*)(E + (size_t)(j0 + r) * G_ + g0 + c4 * 4);
    t[(c4 * 4 + 0) * 72 + r] = f32_to_bf16(v.x);
    t[(c4 * 4 + 1) * 72 + r] = f32_to_bf16(v.y);
    t[(c4 * 4 + 2) * 72 + r] = f32_to_bf16(v.z);
    t[(c4 * 4 + 3) * 72 + r] = f32_to_bf16(v.w);
  }
  __syncthreads();
#pragma unroll
  for (int it = 0; it < 2; ++it) {
    int g = it * 32 + (tid >> 3);
    int ch = tid & 7;
    bf16x8 v = *(const bf16x8*)(&t[g * 72 + ch * 8]);
    *(bf16x8*)(ET + (size_t)(g0 + g) * N_ + j0 + ch * 8) = v;
  }
}

// --- pk: P[i][j] = bf16(exp(q_j - dist(i,j))), partial row sums ---
__global__ __launch_bounds__(256)
void pk_kernel(const unsigned short* __restrict__ encb,
               const float* __restrict__ norms,
               const float2* __restrict__ nq,
               unsigned short* __restrict__ P,     // [N][N] bf16
               float* __restrict__ lpart) {        // [8][N]
  __shared__ __align__(16) unsigned short p_lds[64 * 72];

  const int tid = threadIdx.x;
  const int wave = tid >> 6;
  const int lane = tid & 63;
  const int quad = lane >> 4;
  const int l15 = lane & 15;

  const int i0 = blockIdx.y * 64;
  const int jbase = blockIdx.x * 1024;
  const int irow_a = i0 + 16 * wave + l15;       // A-frag row
  const int iloc_c = 16 * wave + quad * 4;       // local C rows base
  const int irow_c = i0 + iloc_c;

  const int srow_loc = 16 * wave + (lane >> 2);

  bf16x8 afrag[2];
#pragma unroll
  for (int ks = 0; ks < 2; ++ks)
    afrag[ks] = *(const bf16x8*)(encb + (size_t)irow_a * 64 + ks * 32 + quad * 8);

  float ni[4];
#pragma unroll
  for (int r = 0; r < 4; ++r) ni[r] = norms[irow_c + r];

  float lsum[4] = {0.f, 0.f, 0.f, 0.f};

  for (int js = 0; js < 16; ++js) {
    const int j0j = jbase + js * 64;
#pragma unroll
    for (int jt = 0; jt < 4; ++jt) {
      const int jrow = j0j + jt * 16 + l15;
      bf16x8 b0 = *(const bf16x8*)(encb + (size_t)jrow * 64 + quad * 8);
      bf16x8 b1 = *(const bf16x8*)(encb + (size_t)jrow * 64 + 32 + quad * 8);
      float2 njq = nq[jrow];
      f32x4 s4 = {0.f, 0.f, 0.f, 0.f};
      s4 = __builtin_amdgcn_mfma_f32_16x16x32_bf16(afrag[0], b0, s4, 0, 0, 0);
      s4 = __builtin_amdgcn_mfma_f32_16x16x32_bf16(afrag[1], b1, s4, 0, 0, 0);
#pragma unroll
      for (int r = 0; r < 4; ++r) {
        float d2 = fmaxf(ni[r] + njq.x - 2.0f * s4[r], 0.f);
        float sc = njq.y - sqrtf(d2);
        if (irow_c + r == jrow) sc = njq.y;  // exact diagonal: d=0
        float p = __expf(sc);
        unsigned short pb = f32_to_bf16(p);
        lsum[r] += bf16_to_f32(pb);
        p_lds[(iloc_c + r) * 72 + jt * 16 + l15] = pb;
      }
    }
    __syncthreads();
#pragma unroll
    for (int k = 0; k < 2; ++k) {
      int c = (lane & 3) + k * 4;  // chunk 0..7
      bf16x8 v = *(const bf16x8*)(&p_lds[srow_loc * 72 + c * 8]);
      *(bf16x8*)(P + (size_t)(i0 + srow_loc) * N_ + j0j + c * 8) = v;
    }
    __syncthreads();
  }
#pragma unroll
  for (int r = 0; r < 4; ++r) {
    float v = lsum[r];
    v += __shfl_xor(v, 1);
    v += __shfl_xor(v, 2);
    v += __shfl_xor(v, 4);
    v += __shfl_xor(v, 8);
    lsum[r] = v;
  }
  if (l15 == 0) {
#pragma unroll
    for (int r = 0; r < 4; ++r)
      lpart[(size_t)blockIdx.x * N_ + irow_c + r] = lsum[r];
  }
}

// --- inv: linv[i] = 1 / sum_c lpart[c][i] ---
__global__ void inv_kernel(const float* __restrict__ lpart,
                           float* __restrict__ linv) {
  int i = blockIdx.x * blockDim.x + threadIdx.x;
  if (i >= N_) return;
  float s = 0.f;
#pragma unroll
  for (int c = 0; c < 8; ++c) s += lpart[(size_t)c * N_ + i];
  linv[i] = 1.0f / s;
}

// ========= R8 B-direct register-pipelined ring-3 GEMM =========
// out[i][g] = linv[i] * sum_j P[i][j] * ET[g][j]
constexpr int GBM = 256, GBN = 256, GBK = 32;
constexpr int GNT = N_ / GBK;                 // 256 K-tiles
constexpr int SLOT_A = GBM * GBK;             // 8192 shorts (16 KB)
constexpr int GEMM_LDS_BYTES = 3 * SLOT_A * 2;  // 48 KB (dynamic), A-only ring

__global__ __launch_bounds__(512, 2)
void gemm8_kernel(const unsigned short* __restrict__ P,   // [N][N] bf16
                  const unsigned short* __restrict__ ET,  // [G][N] bf16
                  const float* __restrict__ linv,         // [N]
                  float* __restrict__ out) {              // [N][G] f32
  extern __shared__ __align__(16) unsigned short smem[];

  const int tid = threadIdx.x;
  const int wave = tid >> 6;
  const int lane = tid & 63;
  const int quad = lane >> 4;
  const int l15 = lane & 15;

  // XCD-aware tile remap (bijective, 256 = 8*32)
  const int bid = blockIdx.x;
  const int lg = (bid & 7) * 32 + (bid >> 3);
  const int gx = lg & 7;
  const int gy = lg >> 3;
  const int g0 = gx * GBN;
  const int i0 = gy * GBM;

  const int wm = wave >> 2;      // 0..1
  const int wn = wave & 3;       // 0..3
  const int wrow = wm * 128;
  const int wcol = wn * 64;

  // ring slots (A only)
  unsigned short* s0 = smem;
  unsigned short* s1 = smem + SLOT_A;
  unsigned short* s2 = smem + 2 * SLOT_A;

  // ---- A staging: thread -> (row, 16B chunk), XOR chunk swizzle ----
  const int strow = tid >> 2;                  // 0..127
  const int stch = tid & 3;                    // 0..3
  const int csw = stch ^ ((strow >> 1) & 3);
  const int dstA = strow * GBK + stch * 8;     // elements; rows 128-255 at +4096
  unsigned gA0 = (unsigned)(i0 + strow) * N_ + csw * 8;
  unsigned gA1 = (unsigned)(i0 + 128 + strow) * N_ + csw * 8;

  // ---- A frag-read base (swizzle term invariant under row += 16) ----
  const int fswz = (quad ^ ((l15 >> 1) & 3)) * 8;
  const int aBase = (wrow + l15) * GBK + fswz;  // +r*512, +2048+r*512

  // ---- B direct-from-global per-lane offsets (elements; ET < 2^32 elems) ----
  // frag ct: ET[(g0 + wcol + ct*16 + l15) * N_ + u*GBK + quad*8]
  unsigned gBf0 = (unsigned)(g0 + wcol + 0 * 16 + l15) * N_ + quad * 8;
  unsigned gBf1 = (unsigned)(g0 + wcol + 1 * 16 + l15) * N_ + quad * 8;
  unsigned gBf2 = (unsigned)(g0 + wcol + 2 * 16 + l15) * N_ + quad * 8;
  unsigned gBf3 = (unsigned)(g0 + wcol + 3 * 16 + l15) * N_ + quad * 8;

  f32x4 acc[8][4];
#pragma unroll
  for (int a = 0; a < 8; ++a)
#pragma unroll
    for (int b = 0; b < 4; ++b) acc[a][b] = (f32x4){0.f, 0.f, 0.f, 0.f};

  bf16x8 fa0[8], fb0[4], fa1[8], fb1[4];

  // ---- prologue ----
  // queue plan: B(0)x4, A0x2, A1x2 -> vmcnt(2) leaves A1 flying
  fb0[0] = *(const bf16x8*)(ET + gBf0);
  fb0[1] = *(const bf16x8*)(ET + gBf1);
  fb0[2] = *(const bf16x8*)(ET + gBf2);
  fb0[3] = *(const bf16x8*)(ET + gBf3);
  gBf0 += GBK; gBf1 += GBK; gBf2 += GBK; gBf3 += GBK;
  gload_lds16(P + gA0, s0 + dstA);
  gload_lds16(P + gA1, s0 + dstA + 4096);
  gA0 += GBK; gA1 += GBK;
  gload_lds16(P + gA0, s1 + dstA);
  gload_lds16(P + gA1, s1 + dstA + 4096);
  gA0 += GBK; gA1 += GBK;
  asm volatile("s_waitcnt vmcnt(2)" ::: "memory");  // B(0)+A(0) landed
  __builtin_amdgcn_s_barrier();                     // publish A(0)
  {
    const unsigned short* pa = s0 + aBase;
#pragma unroll
    for (int r = 0; r < 4; ++r) fa0[r] = *(const bf16x8*)(pa + r * 512);
#pragma unroll
    for (int r = 0; r < 4; ++r) fa0[4 + r] = *(const bf16x8*)(pa + 2048 + r * 512);
  }
  gload_lds16(P + gA0, s2 + dstA);
  gload_lds16(P + gA1, s2 + dstA + 4096);
  gA0 += GBK; gA1 += GBK;
  asm volatile("s_waitcnt lgkmcnt(0)" ::: "memory"); // fa0 in regs
  asm volatile("s_waitcnt vmcnt(2)" ::: "memory");   // A(1) landed, A(2) flying
  __builtin_amdgcn_s_barrier();                      // publish A(1), free s0
  __builtin_amdgcn_sched_barrier(0);

  unsigned short* cur = s1;  // A(u+1) landed+published
  unsigned short* nxt = s2;  // A(u+2) in flight
  unsigned short* stg = s0;  // free

  int u = 0;
  auto body = [&](bf16x8(&faC)[8], bf16x8(&fbC)[4],
                  bf16x8(&faN)[8], bf16x8(&fbN)[4]) {
    if (u < GNT - 1) {  // B(u+1) -> regs; drains under MFMA
      fbN[0] = *(const bf16x8*)(ET + gBf0);
      fbN[1] = *(const bf16x8*)(ET + gBf1);
      fbN[2] = *(const bf16x8*)(ET + gBf2);
      fbN[3] = *(const bf16x8*)(ET + gBf3);
      gBf0 += GBK; gBf1 += GBK; gBf2 += GBK; gBf3 += GBK;
    }
    if (u < GNT - 3) {  // stage A(u+3) into stg
      gload_lds16(P + gA0, stg + dstA);
      gload_lds16(P + gA1, stg + dstA + 4096);
      gA0 += GBK; gA1 += GBK;
    }
    if (u < GNT - 1) {  // A frags(u+1) from cur; drains under MFMA
      const unsigned short* pa = cur + aBase;
#pragma unroll
      for (int r = 0; r < 4; ++r) faN[r] = *(const bf16x8*)(pa + r * 512);
#pragma unroll
      for (int r = 0; r < 4; ++r) faN[4 + r] = *(const bf16x8*)(pa + 2048 + r * 512);
    }
    __builtin_amdgcn_s_setprio(1);
#pragma unroll
    for (int r = 0; r < 4; ++r)
#pragma unroll
      for (int c = 0; c < 4; ++c)
        acc[r][c] = __builtin_amdgcn_mfma_f32_16x16x32_bf16(faC[r], fbC[c], acc[r][c], 0, 0, 0);
#pragma unroll
    for (int r = 0; r < 4; ++r)
#pragma unroll
      for (int c = 0; c < 4; ++c)
        acc[4 + r][c] = __builtin_amdgcn_mfma_f32_16x16x32_bf16(faC[4 + r], fbC[c], acc[4 + r][c], 0, 0, 0);
    __builtin_amdgcn_s_setprio(0);
    asm volatile("s_waitcnt lgkmcnt(0)" ::: "memory");  // faN in regs
    if (u < GNT - 3) {
      // queue: A(u+2)x2, B(u+1)x4, A(u+3)x2 -> leave A(u+3) only
      asm volatile("s_waitcnt vmcnt(2)" ::: "memory");
    } else {
      asm volatile("s_waitcnt vmcnt(0)" ::: "memory");
    }
    __builtin_amdgcn_s_barrier();  // publish A(u+2); free cur
    __builtin_amdgcn_sched_barrier(0);
    unsigned short* t_ = cur; cur = nxt; nxt = stg; stg = t_;
    ++u;
  };

  for (int it = 0; it < GNT / 2; ++it) {
    body(fa0, fb0, fa1, fb1);
    body(fa1, fb1, fa0, fb0);
  }

  // epilogue
#pragma unroll
  for (int rt = 0; rt < 8; ++rt) {
    float lir[4];
#pragma unroll
    for (int r = 0; r < 4; ++r)
      lir[r] = linv[i0 + wrow + rt * 16 + quad * 4 + r];
#pragma unroll
    for (int ct = 0; ct < 4; ++ct)
#pragma unroll
      for (int r = 0; r < 4; ++r) {
        int row = wrow + rt * 16 + quad * 4 + r;
        int col = wcol + ct * 16 + l15;
        out[(size_t)(i0 + row) * G_ + g0 + col] = acc[rt][ct][r] * lir[r];
      }
  }
}

// ===================== legacy R3 gemm (fallback) =====================
__global__ __launch_bounds__(256, 2)
void gemm_kernel(const unsigned short* __restrict__ P,
                 const unsigned short* __restrict__ ET,
                 const float* __restrict__ linv,
                 float* __restrict__ out) {
  __shared__ __align__(16) unsigned short aT[256 * 64];
  __shared__ __align__(16) unsigned short bT[128 * 64];

  const int tid = threadIdx.x;
  const int wave = tid >> 6;
  const int lane = tid & 63;
  const int quad = lane >> 4;
  const int l15 = lane & 15;

  const int g0 = blockIdx.x * 128;
  const int i0 = blockIdx.y * 256;
  const int wrow = (wave >> 1) * 128;
  const int wcol = (wave & 1) * 64;

  const int strow = tid >> 3;
  const int stc = tid & 7;

  f32x4 acc[8][4];
#pragma unroll
  for (int a = 0; a < 8; ++a)
#pragma unroll
    for (int b = 0; b < 4; ++b) acc[a][b] = (f32x4){0.f, 0.f, 0.f, 0.f};

  for (int kk = 0; kk < N_; kk += 64) {
#pragma unroll
    for (int s = 0; s < 8; ++s) {
      int row = s * 32 + strow;
      int csrc = stc ^ (row & 7);
      gload_lds16(P + (size_t)(i0 + row) * N_ + kk + csrc * 8,
                  &aT[row * 64 + stc * 8]);
    }
#pragma unroll
    for (int s = 0; s < 4; ++s) {
      int row = s * 32 + strow;
      int csrc = stc ^ (row & 7);
      gload_lds16(ET + (size_t)(g0 + row) * N_ + kk + csrc * 8,
                  &bT[row * 64 + stc * 8]);
    }
    __syncthreads();
#pragma unroll
    for (int ks = 0; ks < 2; ++ks) {
      const int swzk = ((ks * 4 + quad) ^ (l15 & 7)) * 8;
      bf16x8 bF[4];
#pragma unroll
      for (int ct = 0; ct < 4; ++ct)
        bF[ct] = *(const bf16x8*)(&bT[(wcol + ct * 16 + l15) * 64 + swzk]);
#pragma unroll
      for (int rt = 0; rt < 8; ++rt) {
        bf16x8 aF = *(const bf16x8*)(&aT[(wrow + rt * 16 + l15) * 64 + swzk]);
#pragma unroll
        for (int ct = 0; ct < 4; ++ct)
          acc[rt][ct] = __builtin_amdgcn_mfma_f32_16x16x32_bf16(aF, bF[ct], acc[rt][ct], 0, 0, 0);
      }
    }
    __syncthreads();
  }

#pragma unroll
  for (int rt = 0; rt < 8; ++rt) {
    float lir[4];
#pragma unroll
    for (int r = 0; r < 4; ++r)
      lir[r] = linv[i0 + wrow + rt * 16 + quad * 4 + r];
#pragma unroll
    for (int ct = 0; ct < 4; ++ct)
#pragma unroll
      for (int r = 0; r < 4; ++r) {
        int row = wrow + rt * 16 + quad * 4 + r;
        int col = wcol + ct * 16 + l15;
        out[(size_t)(i0 + row) * G_ + g0 + col] = acc[rt][ct][r] * lir[r];
      }
  }
}

// ===================== R1 fused fallback (ws too small) =====================
__global__ __launch_bounds__(256, 2)
void fused_kernel(const unsigned short* __restrict__ encb,
                  const float* __restrict__ norms,
                  const float2* __restrict__ nq,
                  const unsigned short* __restrict__ ET,
                  float* __restrict__ out) {
  __shared__ __align__(16) unsigned short p_lds[128 * 72];
  __shared__ __align__(16) unsigned short e_lds[256 * 72];
  __shared__ float linv_lds[128];

  const int tid = threadIdx.x;
  const int wave = tid >> 6;
  const int lane = tid & 63;
  const int quad = lane >> 4;
  const int l15 = lane & 15;
  const int half = lane >> 5;
  const int l31 = lane & 31;

  const int gt = blockIdx.x & 7;
  const int it = blockIdx.x >> 3;
  const int i0 = it * 128;
  const int g0 = gt * 256;

  const int srow = 32 * wave;
  const int wr = wave >> 1, wc = wave & 1;
  const int prow = 64 * wr;
  const int pcol = 128 * wc;

  bf16x8 afrag[2][2];
#pragma unroll
  for (int rt = 0; rt < 2; ++rt)
#pragma unroll
    for (int ks = 0; ks < 2; ++ks)
      afrag[rt][ks] = *(const bf16x8*)(encb +
          (size_t)(i0 + srow + rt * 16 + l15) * 64 + ks * 32 + quad * 8);

  float ni[2][4];
#pragma unroll
  for (int rt = 0; rt < 2; ++rt)
#pragma unroll
    for (int r = 0; r < 4; ++r)
      ni[rt][r] = norms[i0 + srow + rt * 16 + quad * 4 + r];

  float lsum[2][4] = {};
  f32x16 acc[2][4];
#pragma unroll
  for (int a = 0; a < 2; ++a)
#pragma unroll
    for (int b = 0; b < 4; ++b)
#pragma unroll
      for (int e = 0; e < 16; ++e) acc[a][b][e] = 0.f;

  for (int j0j = 0; j0j < N_; j0j += 64) {
#pragma unroll
    for (int s = 0; s < 8; ++s) {
      int g = s * 32 + (tid >> 3);
      int ch = tid & 7;
      bf16x8 v = *(const bf16x8*)(ET + (size_t)(g0 + g) * N_ + j0j + ch * 8);
      *(bf16x8*)(&e_lds[g * 72 + ch * 8]) = v;
    }
#pragma unroll
    for (int jt = 0; jt < 4; ++jt) {
      const int jrow = j0j + jt * 16 + l15;
      bf16x8 b0 = *(const bf16x8*)(encb + (size_t)jrow * 64 + quad * 8);
      bf16x8 b1 = *(const bf16x8*)(encb + (size_t)jrow * 64 + 32 + quad * 8);
      float2 njq = nq[jrow];
#pragma unroll
      for (int rt = 0; rt < 2; ++rt) {
        f32x4 s4 = {0.f, 0.f, 0.f, 0.f};
        s4 = __builtin_amdgcn_mfma_f32_16x16x32_bf16(afrag[rt][0], b0, s4, 0, 0, 0);
        s4 = __builtin_amdgcn_mfma_f32_16x16x32_bf16(afrag[rt][1], b1, s4, 0, 0, 0);
#pragma unroll
        for (int r = 0; r < 4; ++r) {
          int i_loc = srow + rt * 16 + quad * 4 + r;
          float d2 = fmaxf(ni[rt][r] + njq.x - 2.0f * s4[r], 0.f);
          float sc = njq.y - sqrtf(d2);
          if (i0 + i_loc == jrow) sc = njq.y;
          float p = __expf(sc);
          unsigned short pb = f32_to_bf16(p);
          lsum[rt][r] += bf16_to_f32(pb);
          p_lds[i_loc * 72 + jt * 16 + l15] = pb;
        }
      }
    }
    __syncthreads();
#pragma unroll
    for (int ks = 0; ks < 4; ++ks) {
      bf16x8 pa0 = *(const bf16x8*)(&p_lds[(prow + l31) * 72 + ks * 16 + half * 8]);
      bf16x8 pa1 = *(const bf16x8*)(&p_lds[(prow + 32 + l31) * 72 + ks * 16 + half * 8]);
#pragma unroll
      for (int ct = 0; ct < 4; ++ct) {
        bf16x8 eb = *(const bf16x8*)(&e_lds[(pcol + ct * 32 + l31) * 72 + ks * 16 + half * 8]);
        acc[0][ct] = __builtin_amdgcn_mfma_f32_32x32x16_bf16(pa0, eb, acc[0][ct], 0, 0, 0);
        acc[1][ct] = __builtin_amdgcn_mfma_f32_32x32x16_bf16(pa1, eb, acc[1][ct], 0, 0, 0);
      }
    }
    __syncthreads();
  }

#pragma unroll
  for (int rt = 0; rt < 2; ++rt)
#pragma unroll
    for (int r = 0; r < 4; ++r) {
      float v = lsum[rt][r];
      v += __shfl_xor(v, 1);
      v += __shfl_xor(v, 2);
      v += __shfl_xor(v, 4);
      v += __shfl_xor(v, 8);
      lsum[rt][r] = v;
    }
  if (l15 == 0) {
#pragma unroll
    for (int rt = 0; rt < 2; ++rt)
#pragma unroll
      for (int r = 0; r < 4; ++r)
        linv_lds[srow + rt * 16 + quad * 4 + r] = 1.0f / lsum[rt][r];
  }
  __syncthreads();

#pragma unroll
  for (int rt2 = 0; rt2 < 2; ++rt2)
#pragma unroll
    for (int ct = 0; ct < 4; ++ct)
#pragma unroll
      for (int e = 0; e < 16; ++e) {
        int row = prow + rt2 * 32 + (e & 3) + 8 * (e >> 2) + 4 * half;
        int col = pcol + ct * 32 + l31;
        out[(size_t)(i0 + row) * G_ + g0 + col] = acc[rt2][ct][e] * linv_lds[row];
      }
}

extern "C" void kernel_launch(void* const* d_in, const int* in_sizes, int n_in,
                              void* d_out, int out_size, void* d_ws, size_t ws_size,
                              hipStream_t stream) {
  const float* expr = (const float*)d_in[0];  // [N][G]
  const float* enc  = (const float*)d_in[1];  // [N][D]
  const float* qual = (const float*)d_in[2];  // [N]
  float* out = (float*)d_out;                 // [N][G] f32

  char* ws = (char*)d_ws;
  const size_t off_norms = 0;
  const size_t off_nq    = 32768;
  const size_t off_lpart = 98304;                     // 8*8192*4 = 256 KB
  const size_t off_linv  = 360448;
  const size_t off_encb  = 393216;                    // 1 MB
  const size_t off_ET    = 1441792;                   // 32 MB
  const size_t off_P     = 34996224;                  // 128 MB
  const size_t need      = off_P + (size_t)N_ * N_ * 2;  // ~161.4 MiB

  // raise dynamic-LDS limit for gemm8 (once; host-side, capture-safe)
  static bool smem_init = false;
  static bool smem_ok = false;
  if (!smem_init) {
    smem_init = true;
    hipError_t e = hipFuncSetAttribute(
        reinterpret_cast<const void*>(gemm8_kernel),
        hipFuncAttributeMaxDynamicSharedMemorySize, GEMM_LDS_BYTES);
    smem_ok = (e == hipSuccess);
  }

  if (ws_size >= need) {
    float* norms         = (float*)(ws + off_norms);
    float2* nqp          = (float2*)(ws + off_nq);
    float* lpart         = (float*)(ws + off_lpart);
    float* linv          = (float*)(ws + off_linv);
    unsigned short* encb = (unsigned short*)(ws + off_encb);
    unsigned short* ET   = (unsigned short*)(ws + off_ET);
    unsigned short* P    = (unsigned short*)(ws + off_P);

    prep_kernel<<<dim3(N_ / 256), dim3(256), 0, stream>>>(enc, qual, norms, nqp, encb);
    etrans_kernel<<<dim3(N_ / 64, G_ / 64), dim3(256), 0, stream>>>(expr, ET);
    pk_kernel<<<dim3(8, N_ / 64), dim3(256), 0, stream>>>(encb, norms, nqp, P, lpart);
    inv_kernel<<<dim3(N_ / 256), dim3(256), 0, stream>>>(lpart, linv);
    if (smem_ok) {
      gemm8_kernel<<<dim3((N_ / GBM) * (G_ / GBN)), dim3(512), GEMM_LDS_BYTES, stream>>>(
          P, ET, linv, out);
    } else {
      gemm_kernel<<<dim3(G_ / 128, N_ / 256), dim3(256), 0, stream>>>(P, ET, linv, out);
    }
  } else {
    float* norms         = (float*)ws;
    float2* nqp          = (float2*)(ws + 32768);
    unsigned short* encb = (unsigned short*)(ws + 98304);
    unsigned short* ET   = (unsigned short*)(ws + 1146880);
    prep_kernel<<<dim3(N_ / 256), dim3(256), 0, stream>>>(enc, qual, norms, nqp, encb);
    etrans_kernel<<<dim3(N_ / 64, G_ / 64), dim3(256), 0, stream>>>(expr, ET);
    fused_kernel<<<dim3((N_ / 128) * (G_ / 256)), dim3(256), 0, stream>>>(encb, norms, nqp, ET, out);
  }
}

// Round 6
// 406.449 us; speedup vs baseline: 1.3305x; 1.3305x over previous
//
#include <hip/hip_runtime.h>
#include <hip/hip_bf16.h>

// CellSmooth R9:
//  - gemm8_kernel: R6 structure (256x256 tile, 512 thr, 8 waves 2x4,
//    register-pipelined frags, XOR chunk swizzle) with BK=64 double-buffered
//    LDS (128 KB) instead of BK=32 ring-3.  R8 lesson: B-direct doubles L2
//    transactions (16x64B segments waste half of each 128B line) and L2
//    BW/CU < LDS BW -> keep both operands LDS-staged.  R7 lesson: blocks
//    de-correlated but util still 49% -> residual is the per-tile sync
//    epilogue itself.  R9 halves sync points: per K64-tile ONE vmcnt(0)
//    (drains loads issued a full tile earlier -> free) + ONE barrier.
//    Two K32 chunk-steps per tile; frag set X always holds k0, Y holds k1:
//      body(u): Y <- frags(cur,k1); MFMA(X); lgkm; vmcnt(0); barrier;
//               stage(u+2)->cur; X <- frags(oth,k0); MFMA(Y); lgkm; swap.
//    K order identical to R6 -> bitwise-identical output.
//  - pk/prep/etrans/inv unchanged.  Legacy gemm_kernel retained as fallback.

typedef __attribute__((ext_vector_type(8))) short bf16x8;
typedef __attribute__((ext_vector_type(4))) float f32x4;
typedef __attribute__((ext_vector_type(16))) float f32x16;

constexpr int N_ = 8192;
constexpr int G_ = 2048;
constexpr int D_ = 64;

__device__ __forceinline__ unsigned short f32_to_bf16(float f) {
  unsigned u = __builtin_bit_cast(unsigned, f);
  u = (u + 0x7FFFu + ((u >> 16) & 1u)) >> 16;  // RTNE
  return (unsigned short)u;
}
__device__ __forceinline__ float bf16_to_f32(unsigned short h) {
  unsigned u = ((unsigned)h) << 16;
  return __builtin_bit_cast(float, u);
}

typedef __attribute__((address_space(1))) const unsigned int glob_u32;
typedef __attribute__((address_space(3))) unsigned int lds_u32;
__device__ __forceinline__ void gload_lds16(const void* g, void* l) {
  __builtin_amdgcn_global_load_lds((glob_u32*)g, (lds_u32*)l, 16, 0, 0);
}

// --- prep: row norms + packed (norm, quality) + enc -> bf16 ---
__global__ void prep_kernel(const float* __restrict__ enc,
                            const float* __restrict__ quality,
                            float* __restrict__ norms,
                            float2* __restrict__ nq,
                            unsigned short* __restrict__ encb) {
  int row = blockIdx.x * blockDim.x + threadIdx.x;
  if (row >= N_) return;
  const float* r = enc + (size_t)row * D_;
  float n = 0.f;
#pragma unroll
  for (int k = 0; k < D_; k += 4) {
    float4 v = *(const float4*)(r + k);
    n += v.x * v.x + v.y * v.y + v.z * v.z + v.w * v.w;
    ushort4 h;
    h.x = f32_to_bf16(v.x); h.y = f32_to_bf16(v.y);
    h.z = f32_to_bf16(v.z); h.w = f32_to_bf16(v.w);
    *(ushort4*)(encb + (size_t)row * D_ + k) = h;
  }
  norms[row] = n;
  nq[row] = make_float2(n, quality[row]);
}

// --- expression [N][G] f32 -> ET [G][N] bf16 (transpose+convert) ---
__global__ void etrans_kernel(const float* __restrict__ E,
                              unsigned short* __restrict__ ET) {
  __shared__ __align__(16) unsigned short t[64 * 72];
  int j0 = blockIdx.x * 64;
  int g0 = blockIdx.y * 64;
  int tid = threadIdx.x;
#pragma unroll
  for (int it = 0; it < 4; ++it) {
    int r = it * 16 + (tid >> 4);
    int c4 = tid & 15;
    float4 v = *(const float4*)(E + (size_t)(j0 + r) * G_ + g0 + c4 * 4);
    t[(c4 * 4 + 0) * 72 + r] = f32_to_bf16(v.x);
    t[(c4 * 4 + 1) * 72 + r] = f32_to_bf16(v.y);
    t[(c4 * 4 + 2) * 72 + r] = f32_to_bf16(v.z);
    t[(c4 * 4 + 3) * 72 + r] = f32_to_bf16(v.w);
  }
  __syncthreads();
#pragma unroll
  for (int it = 0; it < 2; ++it) {
    int g = it * 32 + (tid >> 3);
    int ch = tid & 7;
    bf16x8 v = *(const bf16x8*)(&t[g * 72 + ch * 8]);
    *(bf16x8*)(ET + (size_t)(g0 + g) * N_ + j0 + ch * 8) = v;
  }
}

// --- pk: P[i][j] = bf16(exp(q_j - dist(i,j))), partial row sums ---
__global__ __launch_bounds__(256)
void pk_kernel(const unsigned short* __restrict__ encb,
               const float* __restrict__ norms,
               const float2* __restrict__ nq,
               unsigned short* __restrict__ P,     // [N][N] bf16
               float* __restrict__ lpart) {        // [8][N]
  __shared__ __align__(16) unsigned short p_lds[64 * 72];

  const int tid = threadIdx.x;
  const int wave = tid >> 6;
  const int lane = tid & 63;
  const int quad = lane >> 4;
  const int l15 = lane & 15;

  const int i0 = blockIdx.y * 64;
  const int jbase = blockIdx.x * 1024;
  const int irow_a = i0 + 16 * wave + l15;       // A-frag row
  const int iloc_c = 16 * wave + quad * 4;       // local C rows base
  const int irow_c = i0 + iloc_c;

  const int srow_loc = 16 * wave + (lane >> 2);

  bf16x8 afrag[2];
#pragma unroll
  for (int ks = 0; ks < 2; ++ks)
    afrag[ks] = *(const bf16x8*)(encb + (size_t)irow_a * 64 + ks * 32 + quad * 8);

  float ni[4];
#pragma unroll
  for (int r = 0; r < 4; ++r) ni[r] = norms[irow_c + r];

  float lsum[4] = {0.f, 0.f, 0.f, 0.f};

  for (int js = 0; js < 16; ++js) {
    const int j0j = jbase + js * 64;
#pragma unroll
    for (int jt = 0; jt < 4; ++jt) {
      const int jrow = j0j + jt * 16 + l15;
      bf16x8 b0 = *(const bf16x8*)(encb + (size_t)jrow * 64 + quad * 8);
      bf16x8 b1 = *(const bf16x8*)(encb + (size_t)jrow * 64 + 32 + quad * 8);
      float2 njq = nq[jrow];
      f32x4 s4 = {0.f, 0.f, 0.f, 0.f};
      s4 = __builtin_amdgcn_mfma_f32_16x16x32_bf16(afrag[0], b0, s4, 0, 0, 0);
      s4 = __builtin_amdgcn_mfma_f32_16x16x32_bf16(afrag[1], b1, s4, 0, 0, 0);
#pragma unroll
      for (int r = 0; r < 4; ++r) {
        float d2 = fmaxf(ni[r] + njq.x - 2.0f * s4[r], 0.f);
        float sc = njq.y - sqrtf(d2);
        if (irow_c + r == jrow) sc = njq.y;  // exact diagonal: d=0
        float p = __expf(sc);
        unsigned short pb = f32_to_bf16(p);
        lsum[r] += bf16_to_f32(pb);
        p_lds[(iloc_c + r) * 72 + jt * 16 + l15] = pb;
      }
    }
    __syncthreads();
#pragma unroll
    for (int k = 0; k < 2; ++k) {
      int c = (lane & 3) + k * 4;  // chunk 0..7
      bf16x8 v = *(const bf16x8*)(&p_lds[srow_loc * 72 + c * 8]);
      *(bf16x8*)(P + (size_t)(i0 + srow_loc) * N_ + j0j + c * 8) = v;
    }
    __syncthreads();
  }
#pragma unroll
  for (int r = 0; r < 4; ++r) {
    float v = lsum[r];
    v += __shfl_xor(v, 1);
    v += __shfl_xor(v, 2);
    v += __shfl_xor(v, 4);
    v += __shfl_xor(v, 8);
    lsum[r] = v;
  }
  if (l15 == 0) {
#pragma unroll
    for (int r = 0; r < 4; ++r)
      lpart[(size_t)blockIdx.x * N_ + irow_c + r] = lsum[r];
  }
}

// --- inv: linv[i] = 1 / sum_c lpart[c][i] ---
__global__ void inv_kernel(const float* __restrict__ lpart,
                           float* __restrict__ linv) {
  int i = blockIdx.x * blockDim.x + threadIdx.x;
  if (i >= N_) return;
  float s = 0.f;
#pragma unroll
  for (int c = 0; c < 8; ++c) s += lpart[(size_t)c * N_ + i];
  linv[i] = 1.0f / s;
}

// ========= R9 BK=64 double-buffered register-pipelined GEMM =========
// out[i][g] = linv[i] * sum_j P[i][j] * ET[g][j]
constexpr int GBM = 256, GBN = 256, GBK = 64;
constexpr int GNT = N_ / GBK;                  // 128 K-tiles
constexpr int SLOT_A = GBM * GBK;              // 16384 shorts (32 KB)
constexpr int SLOT = 2 * SLOT_A;               // A+B = 32768 shorts (64 KB)
constexpr int GEMM_LDS_BYTES = 2 * SLOT * 2;   // 128 KB (double buffer)

__global__ __launch_bounds__(512, 2)
void gemm8_kernel(const unsigned short* __restrict__ P,   // [N][N] bf16
                  const unsigned short* __restrict__ ET,  // [G][N] bf16
                  const float* __restrict__ linv,         // [N]
                  float* __restrict__ out) {              // [N][G] f32
  extern __shared__ __align__(16) unsigned short smem[];

  const int tid = threadIdx.x;
  const int wave = tid >> 6;
  const int lane = tid & 63;
  const int quad = lane >> 4;
  const int l15 = lane & 15;

  // XCD-aware tile remap (bijective, 256 = 8*32)
  const int bid = blockIdx.x;
  const int lg = (bid & 7) * 32 + (bid >> 3);
  const int gx = lg & 7;
  const int gy = lg >> 3;
  const int g0 = gx * GBN;
  const int i0 = gy * GBM;

  const int wm = wave >> 2;      // 0..1
  const int wn = wave & 3;       // 0..3
  const int wrow = wm * 128;
  const int wcol = wn * 64;

  unsigned short* b0 = smem;
  unsigned short* b1 = smem + SLOT;

  // ---- staging: 512 thr x 16B = 8KB/sweep = 64 rows x 128B.  4 sweeps A,
  //      4 sweeps B per K64-tile.  XOR chunk swizzle on the global source;
  //      LDS dest is lane-linear (dst = tid*16B within sweep). ----
  const int strow = tid >> 3;                  // 0..63
  const int stch = tid & 7;                    // 0..7 (16B chunks of 128B row)
  const int csw = stch ^ (strow & 7);          // row&7 invariant across sweeps
  const int dstT = tid * 8;                    // elements within sweep
  unsigned gSA0 = (unsigned)(i0 + 0 * 64 + strow) * N_ + csw * 8;
  unsigned gSA1 = (unsigned)(i0 + 1 * 64 + strow) * N_ + csw * 8;
  unsigned gSA2 = (unsigned)(i0 + 2 * 64 + strow) * N_ + csw * 8;
  unsigned gSA3 = (unsigned)(i0 + 3 * 64 + strow) * N_ + csw * 8;
  unsigned gSB0 = (unsigned)(g0 + 0 * 64 + strow) * N_ + csw * 8;
  unsigned gSB1 = (unsigned)(g0 + 1 * 64 + strow) * N_ + csw * 8;
  unsigned gSB2 = (unsigned)(g0 + 2 * 64 + strow) * N_ + csw * 8;
  unsigned gSB3 = (unsigned)(g0 + 3 * 64 + strow) * N_ + csw * 8;

  // ---- frag-read offsets (elements), swizzle cs = c ^ (row&7), row&7=l15&7
  //      k-chunk 0: c = quad; k-chunk 1: c = 4+quad.  +r*1024 per 16 rows.
  const int sw0 = (quad ^ (l15 & 7)) * 8;
  const int sw1 = ((4 + quad) ^ (l15 & 7)) * 8;
  const int aOff0 = (wrow + l15) * 64 + sw0;
  const int aOff1 = (wrow + l15) * 64 + sw1;
  const int bOff0 = SLOT_A + (wcol + l15) * 64 + sw0;
  const int bOff1 = SLOT_A + (wcol + l15) * 64 + sw1;

  f32x4 acc[8][4];
#pragma unroll
  for (int a = 0; a < 8; ++a)
#pragma unroll
    for (int b = 0; b < 4; ++b) acc[a][b] = (f32x4){0.f, 0.f, 0.f, 0.f};

  bf16x8 faX[8], fbX[4], faY[8], fbY[4];  // X = k0 frags, Y = k1 frags

#define STAGE8(dst)                                            \
  do {                                                         \
    gload_lds16(P + gSA0, (dst) + 0 * 4096 + dstT);            \
    gload_lds16(P + gSA1, (dst) + 1 * 4096 + dstT);            \
    gload_lds16(P + gSA2, (dst) + 2 * 4096 + dstT);            \
    gload_lds16(P + gSA3, (dst) + 3 * 4096 + dstT);            \
    gload_lds16(ET + gSB0, (dst) + SLOT_A + 0 * 4096 + dstT);  \
    gload_lds16(ET + gSB1, (dst) + SLOT_A + 1 * 4096 + dstT);  \
    gload_lds16(ET + gSB2, (dst) + SLOT_A + 2 * 4096 + dstT);  \
    gload_lds16(ET + gSB3, (dst) + SLOT_A + 3 * 4096 + dstT);  \
    gSA0 += GBK; gSA1 += GBK; gSA2 += GBK; gSA3 += GBK;        \
    gSB0 += GBK; gSB1 += GBK; gSB2 += GBK; gSB3 += GBK;        \
  } while (0)

  // ---- prologue: tile0 -> b0, tile1 -> b1 (in flight) ----
  STAGE8(b0);
  STAGE8(b1);
  asm volatile("s_waitcnt vmcnt(8)" ::: "memory");  // tile0 landed (own loads)
  __builtin_amdgcn_s_barrier();                     // publish tile0
  {
    const unsigned short* pb = b0;
#pragma unroll
    for (int c = 0; c < 4; ++c) fbX[c] = *(const bf16x8*)(pb + bOff0 + c * 1024);
#pragma unroll
    for (int r = 0; r < 8; ++r) faX[r] = *(const bf16x8*)(pb + aOff0 + r * 1024);
  }
  asm volatile("s_waitcnt lgkmcnt(0)" ::: "memory");
  __builtin_amdgcn_sched_barrier(0);

  unsigned short* cur = b0;  // tile u (landed+published)
  unsigned short* oth = b1;  // tile u+1 (in flight)

  for (int u = 0; u < GNT; ++u) {
    // Y <- frags(u, k1) from cur; drains under MFMA(X)
#pragma unroll
    for (int c = 0; c < 4; ++c) fbY[c] = *(const bf16x8*)(cur + bOff1 + c * 1024);
#pragma unroll
    for (int r = 0; r < 8; ++r) faY[r] = *(const bf16x8*)(cur + aOff1 + r * 1024);
    __builtin_amdgcn_s_setprio(1);
#pragma unroll
    for (int r = 0; r < 8; ++r)
#pragma unroll
      for (int c = 0; c < 4; ++c)
        acc[r][c] = __builtin_amdgcn_mfma_f32_16x16x32_bf16(faX[r], fbX[c], acc[r][c], 0, 0, 0);
    __builtin_amdgcn_s_setprio(0);
    asm volatile("s_waitcnt lgkmcnt(0)" ::: "memory");  // Y in regs; cur reads done
    asm volatile("s_waitcnt vmcnt(0)" ::: "memory");    // tile u+1 landed (1-tile lead)
    __builtin_amdgcn_s_barrier();  // publish tile u+1; free cur for staging
    __builtin_amdgcn_sched_barrier(0);
    if (u + 2 < GNT) STAGE8(cur);  // tile u+2 into freed buffer
    if (u + 1 < GNT) {             // X <- frags(u+1, k0) from oth; under MFMA(Y)
#pragma unroll
      for (int c = 0; c < 4; ++c) fbX[c] = *(const bf16x8*)(oth + bOff0 + c * 1024);
#pragma unroll
      for (int r = 0; r < 8; ++r) faX[r] = *(const bf16x8*)(oth + aOff0 + r * 1024);
    }
    __builtin_amdgcn_s_setprio(1);
#pragma unroll
    for (int r = 0; r < 8; ++r)
#pragma unroll
      for (int c = 0; c < 4; ++c)
        acc[r][c] = __builtin_amdgcn_mfma_f32_16x16x32_bf16(faY[r], fbY[c], acc[r][c], 0, 0, 0);
    __builtin_amdgcn_s_setprio(0);
    asm volatile("s_waitcnt lgkmcnt(0)" ::: "memory");  // X in regs
    __builtin_amdgcn_sched_barrier(0);
    unsigned short* t_ = cur; cur = oth; oth = t_;
  }
#undef STAGE8

  // epilogue
#pragma unroll
  for (int rt = 0; rt < 8; ++rt) {
    float lir[4];
#pragma unroll
    for (int r = 0; r < 4; ++r)
      lir[r] = linv[i0 + wrow + rt * 16 + quad * 4 + r];
#pragma unroll
    for (int ct = 0; ct < 4; ++ct)
#pragma unroll
      for (int r = 0; r < 4; ++r) {
        int row = wrow + rt * 16 + quad * 4 + r;
        int col = wcol + ct * 16 + l15;
        out[(size_t)(i0 + row) * G_ + g0 + col] = acc[rt][ct][r] * lir[r];
      }
  }
}

// ===================== legacy R3 gemm (fallback) =====================
__global__ __launch_bounds__(256, 2)
void gemm_kernel(const unsigned short* __restrict__ P,
                 const unsigned short* __restrict__ ET,
                 const float* __restrict__ linv,
                 float* __restrict__ out) {
  __shared__ __align__(16) unsigned short aT[256 * 64];
  __shared__ __align__(16) unsigned short bT[128 * 64];

  const int tid = threadIdx.x;
  const int wave = tid >> 6;
  const int lane = tid & 63;
  const int quad = lane >> 4;
  const int l15 = lane & 15;

  const int g0 = blockIdx.x * 128;
  const int i0 = blockIdx.y * 256;
  const int wrow = (wave >> 1) * 128;
  const int wcol = (wave & 1) * 64;

  const int strow = tid >> 3;
  const int stc = tid & 7;

  f32x4 acc[8][4];
#pragma unroll
  for (int a = 0; a < 8; ++a)
#pragma unroll
    for (int b = 0; b < 4; ++b) acc[a][b] = (f32x4){0.f, 0.f, 0.f, 0.f};

  for (int kk = 0; kk < N_; kk += 64) {
#pragma unroll
    for (int s = 0; s < 8; ++s) {
      int row = s * 32 + strow;
      int csrc = stc ^ (row & 7);
      gload_lds16(P + (size_t)(i0 + row) * N_ + kk + csrc * 8,
                  &aT[row * 64 + stc * 8]);
    }
#pragma unroll
    for (int s = 0; s < 4; ++s) {
      int row = s * 32 + strow;
      int csrc = stc ^ (row & 7);
      gload_lds16(ET + (size_t)(g0 + row) * N_ + kk + csrc * 8,
                  &bT[row * 64 + stc * 8]);
    }
    __syncthreads();
#pragma unroll
    for (int ks = 0; ks < 2; ++ks) {
      const int swzk = ((ks * 4 + quad) ^ (l15 & 7)) * 8;
      bf16x8 bF[4];
#pragma unroll
      for (int ct = 0; ct < 4; ++ct)
        bF[ct] = *(const bf16x8*)(&bT[(wcol + ct * 16 + l15) * 64 + swzk]);
#pragma unroll
      for (int rt = 0; rt < 8; ++rt) {
        bf16x8 aF = *(const bf16x8*)(&aT[(wrow + rt * 16 + l15) * 64 + swzk]);
#pragma unroll
        for (int ct = 0; ct < 4; ++ct)
          acc[rt][ct] = __builtin_amdgcn_mfma_f32_16x16x32_bf16(aF, bF[ct], acc[rt][ct], 0, 0, 0);
      }
    }
    __syncthreads();
  }

#pragma unroll
  for (int rt = 0; rt < 8; ++rt) {
    float lir[4];
#pragma unroll
    for (int r = 0; r < 4; ++r)
      lir[r] = linv[i0 + wrow + rt * 16 + quad * 4 + r];
#pragma unroll
    for (int ct = 0; ct < 4; ++ct)
#pragma unroll
      for (int r = 0; r < 4; ++r) {
        int row = wrow + rt * 16 + quad * 4 + r;
        int col = wcol + ct * 16 + l15;
        out[(size_t)(i0 + row) * G_ + g0 + col] = acc[rt][ct][r] * lir[r];
      }
  }
}

// ===================== R1 fused fallback (ws too small) =====================
__global__ __launch_bounds__(256, 2)
void fused_kernel(const unsigned short* __restrict__ encb,
                  const float* __restrict__ norms,
                  const float2* __restrict__ nq,
                  const unsigned short* __restrict__ ET,
                  float* __restrict__ out) {
  __shared__ __align__(16) unsigned short p_lds[128 * 72];
  __shared__ __align__(16) unsigned short e_lds[256 * 72];
  __shared__ float linv_lds[128];

  const int tid = threadIdx.x;
  const int wave = tid >> 6;
  const int lane = tid & 63;
  const int quad = lane >> 4;
  const int l15 = lane & 15;
  const int half = lane >> 5;
  const int l31 = lane & 31;

  const int gt = blockIdx.x & 7;
  const int it = blockIdx.x >> 3;
  const int i0 = it * 128;
  const int g0 = gt * 256;

  const int srow = 32 * wave;
  const int wr = wave >> 1, wc = wave & 1;
  const int prow = 64 * wr;
  const int pcol = 128 * wc;

  bf16x8 afrag[2][2];
#pragma unroll
  for (int rt = 0; rt < 2; ++rt)
#pragma unroll
    for (int ks = 0; ks < 2; ++ks)
      afrag[rt][ks] = *(const bf16x8*)(encb +
          (size_t)(i0 + srow + rt * 16 + l15) * 64 + ks * 32 + quad * 8);

  float ni[2][4];
#pragma unroll
  for (int rt = 0; rt < 2; ++rt)
#pragma unroll
    for (int r = 0; r < 4; ++r)
      ni[rt][r] = norms[i0 + srow + rt * 16 + quad * 4 + r];

  float lsum[2][4] = {};
  f32x16 acc[2][4];
#pragma unroll
  for (int a = 0; a < 2; ++a)
#pragma unroll
    for (int b = 0; b < 4; ++b)
#pragma unroll
      for (int e = 0; e < 16; ++e) acc[a][b][e] = 0.f;

  for (int j0j = 0; j0j < N_; j0j += 64) {
#pragma unroll
    for (int s = 0; s < 8; ++s) {
      int g = s * 32 + (tid >> 3);
      int ch = tid & 7;
      bf16x8 v = *(const bf16x8*)(ET + (size_t)(g0 + g) * N_ + j0j + ch * 8);
      *(bf16x8*)(&e_lds[g * 72 + ch * 8]) = v;
    }
#pragma unroll
    for (int jt = 0; jt < 4; ++jt) {
      const int jrow = j0j + jt * 16 + l15;
      bf16x8 b0 = *(const bf16x8*)(encb + (size_t)jrow * 64 + quad * 8);
      bf16x8 b1 = *(const bf16x8*)(encb + (size_t)jrow * 64 + 32 + quad * 8);
      float2 njq = nq[jrow];
#pragma unroll
      for (int rt = 0; rt < 2; ++rt) {
        f32x4 s4 = {0.f, 0.f, 0.f, 0.f};
        s4 = __builtin_amdgcn_mfma_f32_16x16x32_bf16(afrag[rt][0], b0, s4, 0, 0, 0);
        s4 = __builtin_amdgcn_mfma_f32_16x16x32_bf16(afrag[rt][1], b1, s4, 0, 0, 0);
#pragma unroll
        for (int r = 0; r < 4; ++r) {
          int i_loc = srow + rt * 16 + quad * 4 + r;
          float d2 = fmaxf(ni[rt][r] + njq.x - 2.0f * s4[r], 0.f);
          float sc = njq.y - sqrtf(d2);
          if (i0 + i_loc == jrow) sc = njq.y;
          float p = __expf(sc);
          unsigned short pb = f32_to_bf16(p);
          lsum[rt][r] += bf16_to_f32(pb);
          p_lds[i_loc * 72 + jt * 16 + l15] = pb;
        }
      }
    }
    __syncthreads();
#pragma unroll
    for (int ks = 0; ks < 4; ++ks) {
      bf16x8 pa0 = *(const bf16x8*)(&p_lds[(prow + l31) * 72 + ks * 16 + half * 8]);
      bf16x8 pa1 = *(const bf16x8*)(&p_lds[(prow + 32 + l31) * 72 + ks * 16 + half * 8]);
#pragma unroll
      for (int ct = 0; ct < 4; ++ct) {
        bf16x8 eb = *(const bf16x8*)(&e_lds[(pcol + ct * 32 + l31) * 72 + ks * 16 + half * 8]);
        acc[0][ct] = __builtin_amdgcn_mfma_f32_32x32x16_bf16(pa0, eb, acc[0][ct], 0, 0, 0);
        acc[1][ct] = __builtin_amdgcn_mfma_f32_32x32x16_bf16(pa1, eb, acc[1][ct], 0, 0, 0);
      }
    }
    __syncthreads();
  }

#pragma unroll
  for (int rt = 0; rt < 2; ++rt)
#pragma unroll
    for (int r = 0; r < 4; ++r) {
      float v = lsum[rt][r];
      v += __shfl_xor(v, 1);
      v += __shfl_xor(v, 2);
      v += __shfl_xor(v, 4);
      v += __shfl_xor(v, 8);
      lsum[rt][r] = v;
    }
  if (l15 == 0) {
#pragma unroll
    for (int rt = 0; rt < 2; ++rt)
#pragma unroll
      for (int r = 0; r < 4; ++r)
        linv_lds[srow + rt * 16 + quad * 4 + r] = 1.0f / lsum[rt][r];
  }
  __syncthreads();

#pragma unroll
  for (int rt2 = 0; rt2 < 2; ++rt2)
#pragma unroll
    for (int ct = 0; ct < 4; ++ct)
#pragma unroll
      for (int e = 0; e < 16; ++e) {
        int row = prow + rt2 * 32 + (e & 3) + 8 * (e >> 2) + 4 * half;
        int col = pcol + ct * 32 + l31;
        out[(size_t)(i0 + row) * G_ + g0 + col] = acc[rt2][ct][e] * linv_lds[row];
      }
}

extern "C" void kernel_launch(void* const* d_in, const int* in_sizes, int n_in,
                              void* d_out, int out_size, void* d_ws, size_t ws_size,
                              hipStream_t stream) {
  const float* expr = (const float*)d_in[0];  // [N][G]
  const float* enc  = (const float*)d_in[1];  // [N][D]
  const float* qual = (const float*)d_in[2];  // [N]
  float* out = (float*)d_out;                 // [N][G] f32

  char* ws = (char*)d_ws;
  const size_t off_norms = 0;
  const size_t off_nq    = 32768;
  const size_t off_lpart = 98304;                     // 8*8192*4 = 256 KB
  const size_t off_linv  = 360448;
  const size_t off_encb  = 393216;                    // 1 MB
  const size_t off_ET    = 1441792;                   // 32 MB
  const size_t off_P     = 34996224;                  // 128 MB
  const size_t need      = off_P + (size_t)N_ * N_ * 2;  // ~161.4 MiB

  // raise dynamic-LDS limit for gemm8 (once; host-side, capture-safe)
  static bool smem_init = false;
  static bool smem_ok = false;
  if (!smem_init) {
    smem_init = true;
    hipError_t e = hipFuncSetAttribute(
        reinterpret_cast<const void*>(gemm8_kernel),
        hipFuncAttributeMaxDynamicSharedMemorySize, GEMM_LDS_BYTES);
    smem_ok = (e == hipSuccess);
  }

  if (ws_size >= need) {
    float* norms         = (float*)(ws + off_norms);
    float2* nqp          = (float2*)(ws + off_nq);
    float* lpart         = (float*)(ws + off_lpart);
    float* linv          = (float*)(ws + off_linv);
    unsigned short* encb = (unsigned short*)(ws + off_encb);
    unsigned short* ET   = (unsigned short*)(ws + off_ET);
    unsigned short* P    = (unsigned short*)(ws + off_P);

    prep_kernel<<<dim3(N_ / 256), dim3(256), 0, stream>>>(enc, qual, norms, nqp, encb);
    etrans_kernel<<<dim3(N_ / 64, G_ / 64), dim3(256), 0, stream>>>(expr, ET);
    pk_kernel<<<dim3(8, N_ / 64), dim3(256), 0, stream>>>(encb, norms, nqp, P, lpart);
    inv_kernel<<<dim3(N_ / 256), dim3(256), 0, stream>>>(lpart, linv);
    if (smem_ok) {
      gemm8_kernel<<<dim3((N_ / GBM) * (G_ / GBN)), dim3(512), GEMM_LDS_BYTES, stream>>>(
          P, ET, linv, out);
    } else {
      gemm_kernel<<<dim3(G_ / 128, N_ / 256), dim3(256), 0, stream>>>(P, ET, linv, out);
    }
  } else {
    float* norms         = (float*)ws;
    float2* nqp          = (float2*)(ws + 32768);
    unsigned short* encb = (unsigned short*)(ws + 98304);
    unsigned short* ET   = (unsigned short*)(ws + 1146880);
    prep_kernel<<<dim3(N_ / 256), dim3(256), 0, stream>>>(enc, qual, norms, nqp, encb);
    etrans_kernel<<<dim3(N_ / 64, G_ / 64), dim3(256), 0, stream>>>(expr, ET);
    fused_kernel<<<dim3((N_ / 128) * (G_ / 256)), dim3(256), 0, stream>>>(encb, norms, nqp, ET, out);
  }
}